// Round 3
// baseline (74.586 us; speedup 1.0000x reference)
//
#include <hip/hip_runtime.h>
#include <math.h>

// KAN dense layer, MI355X. N_IN=N_OUT=128, K=3, G=8, BATCH=512.
// Uniform grid => closed-form cubic B-spline, only 4 nonzero basis fns per x.
// v3: pre-kernel repacks cspl*c_basis into W4[e][slot 0..7][4] fp32 (16B-aligned,
//     one 64B cache line per (e, b-octet)) so the inner gather is a single
//     global_load_dwordx4 instead of 4x global_load_dword (v2 was TA/VMEM-issue
//     bound: 524K wave-gathers x ~16 lines). cspl folded into W4.
#define N_IN  128
#define N_OUT 128
#define BATCH 512
#define NK    11      // G+K coeffs per edge
#define TB    8       // batch tile
#define TO    8       // output tile

// W4[e][slot][k] = cspl[e] * c_basis[e, slot+k],  e = o*128+i, slot in 0..7, k in 0..3
__global__ __launch_bounds__(256) void w4_build(
    const float* __restrict__ cbasis,   // [16384][11]
    const float* __restrict__ cspl,     // [16384] flat
    float* __restrict__ w4)             // [16384][8][4]
{
    const int t = blockIdx.x * 256 + threadIdx.x;   // 0..131071
    const int e = t >> 3, slot = t & 7;
    const float s = cspl[e];
    const float* r = cbasis + e * NK + slot;
    float4 v = make_float4(s * r[0], s * r[1], s * r[2], s * r[3]);
    *(float4*)(w4 + (size_t)t * 4) = v;             // coalesced 16B/lane
}

__global__ __launch_bounds__(256) void kan_kernel(
    const float* __restrict__ x,       // [512][128]
    const float* __restrict__ w4,      // [16384][8][4] repacked coeffs
    const float* __restrict__ cres,    // [128][128]
    const float* __restrict__ bias,    // [128]
    float* __restrict__ y)             // [512][128]
{
    // Bank check (32 banks, dword-indexed):
    //  sBv stride 516 (516%32=4): 8 b-lanes -> b128 first-banks 4*b_l, distinct. OK
    //  sEx stride 258 (258%32=2): b64 first-banks 2*b_l+2i, distinct evens.   OK
    //  sCW stride 129 (129%32=1): b32 banks o_l+i, distinct; same-o broadcast. OK
    __shared__ float sBv[TB * 516];          // 4 basis values per (b,i), fp32
    __shared__ float sEx[TB * 258];          // (silu, base*4 as int) per (b,i)
    __shared__ float sCW[TO * 129];          // cres per (o,i)
    __shared__ float sRed[256];

    const int b0 = blockIdx.x * TB;          // 64 blocks in x
    const int o0 = blockIdx.y * TO;          // 16 blocks in y
    const int t  = threadIdx.x;

    // ---------- Phase 1: basis + silu for TB x 128 inputs ----------
    for (int p = t; p < TB * N_IN; p += 256) {
        const int b_l = p >> 7, i = p & 127;
        const float xv = x[(b0 + b_l) * N_IN + i];
        const float u  = (xv + 1.75f) * 4.0f;   // u in [3,11)
        float jf = floorf(u);
        jf = fminf(fmaxf(jf, 3.0f), 10.0f);
        const float tt  = u - jf;
        const float omt = 1.0f - tt;
        const float t2 = tt * tt, t3 = t2 * tt;
        const float B0 = omt * omt * omt * (1.0f / 6.0f);
        const float B1 = (3.0f * t3 - 6.0f * t2 + 4.0f) * (1.0f / 6.0f);
        const float B2 = (-3.0f * t3 + 3.0f * t2 + 3.0f * tt + 1.0f) * (1.0f / 6.0f);
        const float B3 = t3 * (1.0f / 6.0f);
        const int boff = ((int)jf - 3) * 4;      // slot offset in floats, 0..28
        const float sig  = 1.0f / (1.0f + __expf(-xv));
        const float silu = xv * sig;
        *(float4*)&sBv[b_l * 516 + i * 4] = make_float4(B0, B1, B2, B3);
        *(float2*)&sEx[b_l * 258 + i * 2] = make_float2(silu, __int_as_float(boff));
    }
    // Stage c_res tile (coalesced)
    for (int p = t; p < TO * N_IN; p += 256) {
        const int o_l = p >> 7, i = p & 127;
        sCW[o_l * 129 + i] = cres[(o0 + o_l) * N_IN + i];
    }
    __syncthreads();

    // ---------- Phase 2: thread = (b_l, o_l, i-quarter) ----------
    const int b_l = t & 7;
    const int o_l = (t >> 3) & 7;
    const int h   = t >> 6;                  // wave-uniform: 0..3 quarter of i
    const int o   = o0 + o_l;
    const int i0  = h * 32;

    const float2* exBase = (const float2*)&sEx[b_l * 258];
    const float4* bvBase = (const float4*)&sBv[b_l * 516];
    const float*  cwBase = &sCW[o_l * 129];
    // W4 row for (o, i): floats offset (o*128+i)*32
    const float*  w4row  = w4 + ((size_t)(o * N_IN + i0) << 5);

    float acc = 0.0f;
#pragma unroll 8
    for (int ii = 0; ii < 32; ++ii) {
        const int i = i0 + ii;
        const float2 ex = exBase[i];
        const float4 bv = bvBase[i];
        const float cr  = cwBase[i];
        const int boff  = __float_as_int(ex.y);
        const float4 cv = *(const float4*)(w4row + boff);  // 16B-aligned gather
        acc = fmaf(cv.x, bv.x, acc);
        acc = fmaf(cv.y, bv.y, acc);
        acc = fmaf(cv.z, bv.z, acc);
        acc = fmaf(cv.w, bv.w, acc);
        acc = fmaf(cr, ex.x, acc);
        w4row += 32;
    }

    sRed[t] = acc;
    __syncthreads();
    if (h == 0) {
        const float tot = sRed[t] + sRed[t + 64] + sRed[t + 128] + sRed[t + 192]
                        + bias[o];
        y[(b0 + b_l) * N_OUT + o] = tot;
    }
}

extern "C" void kernel_launch(void* const* d_in, const int* in_sizes, int n_in,
                              void* d_out, int out_size, void* d_ws, size_t ws_size,
                              hipStream_t stream) {
    const float* x      = (const float*)d_in[0];
    // d_in[1] = knots: unused — uniform grid is known in closed form
    const float* cbasis = (const float*)d_in[2];
    const float* cspl   = (const float*)d_in[3];
    const float* cres   = (const float*)d_in[4];
    const float* bias   = (const float*)d_in[5];
    float* y  = (float*)d_out;
    float* w4 = (float*)d_ws;                 // 16384*8*4*4 B = 2 MB scratch

    w4_build<<<512, 256, 0, stream>>>(cbasis, cspl, w4);
    dim3 grid(BATCH / TB, N_OUT / TO);        // 64 x 16 = 1024 blocks
    kan_kernel<<<grid, 256, 0, stream>>>(x, w4, cres, bias, y);
}